// Round 10
// baseline (1222.904 us; speedup 1.0000x reference)
//
#include <hip/hip_runtime.h>
#include <cmath>
#include <cstdint>
#include <cstddef>
#include <climits>

#define N_SRC 65536
#define N_TGT 1024
#define DIM   256
#define TAU_INV (1.0f/0.07f)
#define LOSS_EPS 1e-6f
#define TOPSEL 512
#define N_CLASSES 345
#define SLICE_R 64
#define NS (N_SRC/SLICE_R)     // 1024 row-slices

typedef __bf16 bf16x8 __attribute__((ext_vector_type(8)));
typedef float  f32x4  __attribute__((ext_vector_type(4)));

// ---------------- bf16 split helpers ------------------------------------------------
__device__ __forceinline__ unsigned short f2bf(float x) {
  unsigned u = __float_as_uint(x);
  unsigned r = (u + 0x7fffu + ((u >> 16) & 1u)) >> 16;
  return (unsigned short)r;
}
__device__ __forceinline__ float bf2f(unsigned short h) {
  return __uint_as_float(((unsigned)h) << 16);
}

// ---------------- top-5 insertion helpers -------------------------------------------
__device__ __forceinline__ void insert5_vi(float v[5], int id[5], float nv, int ni) {
  bool beats_last = (nv > v[4]) || (nv == v[4] && ni < id[4]);
  if (!beats_last) return;
  #pragma unroll
  for (int p = 4; p > 0; --p) {
    bool up = (nv > v[p-1]) || (nv == v[p-1] && ni < id[p-1]);
    if (up) { v[p] = v[p-1]; id[p] = id[p-1]; }
    else    { v[p] = nv; id[p] = ni; return; }
  }
  v[0] = nv; id[0] = ni;
}
__device__ __forceinline__ void insert5_v(float v[5], float nv) {
  if (!(nv > v[4])) return;
  #pragma unroll
  for (int p = 4; p > 0; --p) {
    if (nv > v[p-1]) v[p] = v[p-1];
    else { v[p] = nv; return; }
  }
  v[0] = nv;
}
__device__ __forceinline__ void wave_merge5_vi(float v[5], int id[5]) {
  #pragma unroll
  for (int off = 1; off < 64; off <<= 1) {
    float pv[5]; int pi[5];
    #pragma unroll
    for (int u = 0; u < 5; ++u) {
      pv[u] = __shfl_xor(v[u], off, 64);
      pi[u] = __shfl_xor(id[u], off, 64);
    }
    #pragma unroll
    for (int u = 0; u < 5; ++u) insert5_vi(v, id, pv[u], pi[u]);
  }
}
__device__ __forceinline__ void wave_merge5_v(float v[5]) {
  #pragma unroll
  for (int off = 1; off < 64; off <<= 1) {
    float pv[5];
    #pragma unroll
    for (int u = 0; u < 5; ++u) pv[u] = __shfl_xor(v[u], off, 64);
    #pragma unroll
    for (int u = 0; u < 5; ++u) insert5_v(v, pv[u]);
  }
}

// ---------------- preprocessing: counting sort of rows by label ---------------------
__global__ __launch_bounds__(512) void k_zero(int* __restrict__ hist) {
  if (threadIdx.x < N_CLASSES) hist[threadIdx.x] = 0;
}
__global__ __launch_bounds__(256) void k_hist(const int* __restrict__ labels,
                                              int* __restrict__ hist) {
  int i = blockIdx.x * 256 + threadIdx.x;
  atomicAdd(&hist[labels[i]], 1);
}
__global__ __launch_bounds__(64) void k_scan(const int* __restrict__ hist,
                                             int* __restrict__ start,
                                             int* __restrict__ cursor) {
  if (threadIdx.x == 0) {
    int acc = 0;
    for (int c = 0; c < N_CLASSES; ++c) {
      start[c] = acc; cursor[c] = acc; acc += hist[c];
    }
    start[N_CLASSES] = acc;
  }
}
__global__ __launch_bounds__(256) void k_perm(const int* __restrict__ labels,
                                              int* __restrict__ cursor,
                                              int* __restrict__ g,
                                              int* __restrict__ sortedLab) {
  int i = blockIdx.x * 256 + threadIdx.x;
  int l = labels[i];
  int slot = atomicAdd(&cursor[l], 1);
  g[slot] = i;
  sortedLab[slot] = l;
}

// ---------------- K1: row-normalize + split fp32 -> (hi, lo) bf16 -------------------
__global__ __launch_bounds__(256) void k_norm_split(const float* __restrict__ X,
                                                    const int* __restrict__ g,
                                                    unsigned short* __restrict__ hi,
                                                    unsigned short* __restrict__ lo) {
  int wave = threadIdx.x >> 6, lane = threadIdx.x & 63;
  int row  = blockIdx.x * 4 + wave;
  int src  = g ? g[row] : row;
  float4 v = reinterpret_cast<const float4*>(X + (size_t)src * DIM)[lane];
  float ss = v.x*v.x + v.y*v.y + v.z*v.z + v.w*v.w;
  #pragma unroll
  for (int o = 32; o > 0; o >>= 1) ss += __shfl_xor(ss, o, 64);
  float r = 1.0f / sqrtf(ss);
  v.x *= r; v.y *= r; v.z *= r; v.w *= r;
  ushort4 h, l;
  h.x = f2bf(v.x); l.x = f2bf(v.x - bf2f(h.x));
  h.y = f2bf(v.y); l.y = f2bf(v.y - bf2f(h.y));
  h.z = f2bf(v.z); l.z = f2bf(v.z - bf2f(h.z));
  h.w = f2bf(v.w); l.w = f2bf(v.w - bf2f(h.w));
  reinterpret_cast<ushort4*>(hi + (size_t)row * DIM)[lane] = h;
  reinterpret_cast<ushort4*>(lo + (size_t)row * DIM)[lane] = l;
}

// ---------------- K2: split-bf16 MFMA GEMM, transposed output sim[i][j] -------------
// R0's measured-fastest structure. A = targets, B = sources; float4 store covers
// 4 consecutive j at fixed i. 1-D grid with bijective XCD swizzle: the nby blocks
// sharing one A panel run consecutively on one XCD -> A fetched once per chunk.
__device__ __forceinline__ void gl_lds(const unsigned short* g, unsigned short* d) {
  __builtin_amdgcn_global_load_lds(
      (const __attribute__((address_space(1))) unsigned int*)g,
      (__attribute__((address_space(3))) unsigned int*)d, 16, 0, 0);
}

__global__ __launch_bounds__(256) void k_gemm(
    const unsigned short* __restrict__ Ahi, const unsigned short* __restrict__ Alo,  // targets
    const unsigned short* __restrict__ Bhi, const unsigned short* __restrict__ Blo,  // sources
    float* __restrict__ simIJ, int cols, int j_off)
{
  __shared__ unsigned short As_hi[128*32];
  __shared__ unsigned short As_lo[128*32];
  __shared__ unsigned short Bs_hi[128*32];
  __shared__ unsigned short Bs_lo[128*32];

  const int tid  = threadIdx.x;
  const int lane = tid & 63;
  const int w    = tid >> 6;       // wave 0..3
  const int wm   = w & 1;          // target-dim half (M)
  const int wn   = w >> 1;         // source-dim half (N)

  // XCD-locality swizzle: c = XCD, k/nby = source block, k%nby = target block
  const int nby = cols >> 7;
  const int d   = blockIdx.x;                  // grid = 512 * nby (multiple of 8)
  const int c   = d & 7;
  const int kk  = d >> 3;
  const int by  = kk % nby;
  const int bx  = (kk / nby) * 8 + c;
  const int i0   = bx * 128;                   // source block
  const int j0g  = j_off + by * 128;           // global target row (A loads)
  const int j0l  = by * 128;                   // chunk-local target

  f32x4 acc[4][4];
  #pragma unroll
  for (int a = 0; a < 4; ++a)
    #pragma unroll
    for (int b = 0; b < 4; ++b) acc[a][b] = f32x4{0.f, 0.f, 0.f, 0.f};

  const int srow = (w << 5) + (lane >> 2);
  const int scol = (lane & 3) << 3;             // 8 bf16 = 16 B
  const unsigned short* gAh = Ahi + (size_t)(j0g + srow) * DIM + scol;
  const unsigned short* gAl = Alo + (size_t)(j0g + srow) * DIM + scol;
  const unsigned short* gBh = Bhi + (size_t)(i0  + srow) * DIM + scol;
  const unsigned short* gBl = Blo + (size_t)(i0  + srow) * DIM + scol;
  unsigned short* dA0  = &As_hi[(w << 5) * 32];
  unsigned short* dA1  = &As_hi[((w << 5) + 16) * 32];
  unsigned short* dB0  = &Bs_hi[(w << 5) * 32];
  unsigned short* dB1  = &Bs_hi[((w << 5) + 16) * 32];
  unsigned short* dA0l = &As_lo[(w << 5) * 32];
  unsigned short* dA1l = &As_lo[((w << 5) + 16) * 32];
  unsigned short* dB0l = &Bs_lo[(w << 5) * 32];
  unsigned short* dB1l = &Bs_lo[((w << 5) + 16) * 32];

  const int fr = lane & 15;
  const int fk = (lane >> 4) << 3;

  for (int k0 = 0; k0 < DIM; k0 += 32) {
    __syncthreads();
    gl_lds(gAh + k0,           dA0);
    gl_lds(gAh + k0 + 16*DIM,  dA1);
    gl_lds(gAl + k0,           dA0l);
    gl_lds(gAl + k0 + 16*DIM,  dA1l);
    gl_lds(gBh + k0,           dB0);
    gl_lds(gBh + k0 + 16*DIM,  dB1);
    gl_lds(gBl + k0,           dB0l);
    gl_lds(gBl + k0 + 16*DIM,  dB1l);
    __syncthreads();

    bf16x8 ah[4], al[4], bh[4], bl[4];
    #pragma unroll
    for (int rf = 0; rf < 4; ++rf) {
      int r = ((wm << 6) + (rf << 4) + fr) * 32 + fk;
      ah[rf] = *(const bf16x8*)&As_hi[r];
      al[rf] = *(const bf16x8*)&As_lo[r];
    }
    #pragma unroll
    for (int cf = 0; cf < 4; ++cf) {
      int r = ((wn << 6) + (cf << 4) + fr) * 32 + fk;
      bh[cf] = *(const bf16x8*)&Bs_hi[r];
      bl[cf] = *(const bf16x8*)&Bs_lo[r];
    }
    #pragma unroll
    for (int rf = 0; rf < 4; ++rf)
      #pragma unroll
      for (int cf = 0; cf < 4; ++cf) {
        acc[rf][cf] = __builtin_amdgcn_mfma_f32_16x16x32_bf16(ah[rf], bh[cf], acc[rf][cf], 0, 0, 0);
        acc[rf][cf] = __builtin_amdgcn_mfma_f32_16x16x32_bf16(ah[rf], bl[cf], acc[rf][cf], 0, 0, 0);
        acc[rf][cf] = __builtin_amdgcn_mfma_f32_16x16x32_bf16(al[rf], bh[cf], acc[rf][cf], 0, 0, 0);
      }
  }

  // store: m (reg dim) = target j-local, n (lane&15) = source i-local
  #pragma unroll
  for (int rf = 0; rf < 4; ++rf) {
    const int m_base = (wm << 6) + (rf << 4) + ((lane >> 4) << 2);
    #pragma unroll
    for (int cf = 0; cf < 4; ++cf) {
      const int n = (wn << 6) + (cf << 4) + (lane & 15);
      *reinterpret_cast<float4*>(&simIJ[(size_t)(i0 + n) * cols + j0l + m_base]) =
          make_float4(acc[rf][cf][0], acc[rf][cf][1], acc[rf][cf][2], acc[rf][cf][3]);
    }
  }
}

// ---------------- K3: per-slice per-column top-5 + sum-exp (thread owns 4 cols) -----
// Block = slice of 64 rows; cols/4 threads each own 4 consecutive columns and stream
// rows serially as float4 (16 B/lane, G13 sweet spot; wave reads 1KB contiguous).
// 4 independent top-5 + sum chains per thread = ILP for latency hiding. No merges.
__global__ __launch_bounds__(256) void k_part1t4(const float* __restrict__ sim,
                                                 int cols,
                                                 float* __restrict__ p1v,
                                                 int* __restrict__ p1i,
                                                 float* __restrict__ pse) {
  const int s  = blockIdx.x;
  const int jc = threadIdx.x * 4;
  if (jc >= cols) return;
  float tv[4][5]; int ti[4][5]; float se[4];
  #pragma unroll
  for (int q = 0; q < 4; ++q) {
    #pragma unroll
    for (int u = 0; u < 5; ++u) { tv[q][u] = -INFINITY; ti[q][u] = INT_MAX; }
    se[q] = 0.f;
  }
  const int i0 = s * SLICE_R;
  const float4* p = reinterpret_cast<const float4*>(sim + (size_t)i0 * cols + jc);
  const int rstride = cols >> 2;            // float4s per row
  #pragma unroll 8
  for (int it = 0; it < SLICE_R; ++it) {
    float4 v = p[(size_t)it * rstride];
    const int i = i0 + it;
    se[0] += __expf(v.x * TAU_INV);
    se[1] += __expf(v.y * TAU_INV);
    se[2] += __expf(v.z * TAU_INV);
    se[3] += __expf(v.w * TAU_INV);
    if (v.x > tv[0][4]) insert5_vi(tv[0], ti[0], v.x, i);
    if (v.y > tv[1][4]) insert5_vi(tv[1], ti[1], v.y, i);
    if (v.z > tv[2][4]) insert5_vi(tv[2], ti[2], v.z, i);
    if (v.w > tv[3][4]) insert5_vi(tv[3], ti[3], v.w, i);
  }
  #pragma unroll
  for (int q = 0; q < 4; ++q) {
    const size_t o = ((size_t)s * cols + jc + q) * 5;
    #pragma unroll
    for (int u = 0; u < 5; ++u) { p1v[o+u] = tv[q][u]; p1i[o+u] = ti[q][u]; }
    pse[(size_t)s * cols + jc + q] = se[q];
  }
}

// ---------------- K4: merge slice top-5s -> assigned label per column ---------------
__global__ __launch_bounds__(256) void k_assign(const float* __restrict__ p1v,
                                                const int* __restrict__ p1i,
                                                const int* __restrict__ sortedLab,
                                                int* __restrict__ assigned,
                                                int cols, int j_off) {
  const int w = threadIdx.x >> 6, lane = threadIdx.x & 63;
  const int jloc = blockIdx.x * 4 + w;
  float v[5]; int id[5];
  #pragma unroll
  for (int u = 0; u < 5; ++u) { v[u] = -INFINITY; id[u] = INT_MAX; }
  #pragma unroll
  for (int r = 0; r < NS/64; ++r) {
    const int s = r * 64 + lane;
    const size_t o = ((size_t)s * cols + jloc) * 5;
    #pragma unroll
    for (int u = 0; u < 5; ++u) insert5_vi(v, id, p1v[o+u], p1i[o+u]);
  }
  wave_merge5_vi(v, id);
  if (lane == 0) {
    int lab[5];
    #pragma unroll
    for (int a = 0; a < 5; ++a) lab[a] = sortedLab[id[a]];
    int bestSc = INT_MIN, bestA = 0;
    #pragma unroll
    for (int a = 0; a < 5; ++a) {
      int c = 0;
      #pragma unroll
      for (int b = 0; b < 5; ++b) c += (lab[b] == lab[a]) ? 1 : 0;
      int sc = c * 1000000 - lab[a];
      if (sc > bestSc) { bestSc = sc; bestA = a; }
    }
    assigned[j_off + jloc] = lab[bestA];
  }
}

// ---------------- K5: targeted pass2 (wave per column) ------------------------------
// Matched rows = [start[asg], start[asg+1]) span a few 64-row slices (label-sorted).
// Stream covering slices; fold stored top-5s of all other slices into ut (provably
// unmatched); se = sum pse. Score+contrast inline.
__global__ __launch_bounds__(256) void k_part2n(const float* __restrict__ sim,
                                                const int* __restrict__ assigned,
                                                const int* __restrict__ start,
                                                const float* __restrict__ p1v,
                                                const float* __restrict__ pse,
                                                float* __restrict__ scores,
                                                float* __restrict__ contrast,
                                                int cols, int j_off) {
  const int w = threadIdx.x >> 6, lane = threadIdx.x & 63;
  const int jloc = blockIdx.x * 4 + w;
  const int j    = j_off + jloc;
  const int asg  = assigned[j];
  const int a    = start[asg];
  const int b    = start[asg + 1];
  const int s0   = a >> 6;
  const int s1   = (b - 1) >> 6;

  float mt[5], ut[5]; float sem = 0.f, se = 0.f;
  #pragma unroll
  for (int u = 0; u < 5; ++u) { mt[u] = -INFINITY; ut[u] = -INFINITY; }

  for (int i = s0 * SLICE_R + lane; i < (s1 + 1) * SLICE_R; i += 64) {
    float v = sim[(size_t)i * cols + jloc];
    if (i >= a && i < b) { sem += __expf(v * TAU_INV); insert5_v(mt, v); }
    else insert5_v(ut, v);
  }
  #pragma unroll
  for (int r = 0; r < NS/64; ++r) {
    const int s = r * 64 + lane;
    se += pse[(size_t)s * cols + jloc];
    if (s < s0 || s > s1) {
      const size_t o = ((size_t)s * cols + jloc) * 5;
      #pragma unroll
      for (int u = 0; u < 5; ++u) insert5_v(ut, p1v[o+u]);
    }
  }
  #pragma unroll
  for (int o = 32; o > 0; o >>= 1) { sem += __shfl_xor(sem, o, 64); se += __shfl_xor(se, o, 64); }
  wave_merge5_v(mt);
  wave_merge5_v(ut);
  if (lane == 0) {
    float nln = 0.f, nun = 0.f;
    #pragma unroll
    for (int u = 0; u < 5; ++u) {
      if (mt[u] > -1e30f) nln += mt[u];
      if (ut[u] > -1e30f) nun += ut[u];
    }
    scores[j]   = nln / nun;
    contrast[j] = sem / se;
  }
}

// ---------------- K6: top-512 selection + loss --------------------------------------
__global__ __launch_bounds__(1024) void k_finalize(const float* __restrict__ scores,
                                                   const float* __restrict__ contrast,
                                                   float* __restrict__ out) {
  __shared__ float sc[N_TGT];
  __shared__ float red[N_TGT];
  const int j = threadIdx.x;
  sc[j] = scores[j];
  __syncthreads();
  float my = sc[j];
  int rank = 0;
  for (int m = 0; m < N_TGT; ++m) {
    float s = sc[m];
    rank += ((s > my) || (s == my && m < j)) ? 1 : 0;
  }
  red[j] = (rank < TOPSEL) ? logf(contrast[j] + LOSS_EPS) : 0.0f;
  __syncthreads();
  for (int s = 512; s > 0; s >>= 1) { if (j < s) red[j] += red[j+s]; __syncthreads(); }
  if (j == 0) out[0] = -red[0] / (float)TOPSEL;
}

// ---------------- launcher ----------------------------------------------------------
extern "C" void kernel_launch(void* const* d_in, const int* in_sizes, int n_in,
                              void* d_out, int out_size, void* d_ws, size_t ws_size,
                              hipStream_t stream) {
  const float* S      = (const float*)d_in[0];
  const int*   labels = (const int*)d_in[1];
  const float* T      = (const float*)d_in[2];
  float* out = (float*)d_out;

  float* ws = (float*)d_ws;
  float* scores    = ws;                                    // 1024
  float* contrastA = scores + N_TGT;                        // 1024
  int*   assigned  = (int*)(contrastA + N_TGT);             // 1024
  float* p1v       = (float*)(assigned + N_TGT);            // NS*1024*5 = 5.24M f
  int*   p1i       = (int*)(p1v + (size_t)NS*N_TGT*5);      // 5.24M i
  float* pse       = (float*)(p1i + (size_t)NS*N_TGT*5);    // NS*1024 = 1.05M f
  int*   hist      = (int*)(pse + (size_t)NS*N_TGT);        // 345
  int*   startArr  = hist + N_CLASSES;                      // 346
  int*   cursor    = startArr + (N_CLASSES + 1);            // 345
  int*   gidx      = cursor + N_CLASSES;                    // 65536
  int*   sortedLab = gidx + N_SRC;                          // 65536
  unsigned short* Shi = (unsigned short*)(sortedLab + N_SRC);
  unsigned short* Slo = Shi + (size_t)N_SRC*DIM;
  unsigned short* Thi = Slo + (size_t)N_SRC*DIM;
  unsigned short* Tlo = Thi + (size_t)N_TGT*DIM;
  float* simbuf       = (float*)(Tlo + (size_t)N_TGT*DIM);

  size_t head  = (size_t)(simbuf - ws);
  size_t avail = (ws_size / 4 > head) ? (ws_size / 4 - head) : 0;
  int cols = 128;
  if      (avail >= (size_t)1024 * N_SRC) cols = 1024;
  else if (avail >= (size_t)512  * N_SRC) cols = 512;
  else if (avail >= (size_t)256  * N_SRC) cols = 256;

  // preprocessing: counting sort of source rows by label
  k_zero<<<1, 512, 0, stream>>>(hist);
  k_hist<<<N_SRC/256, 256, 0, stream>>>(labels, hist);
  k_scan<<<1, 64, 0, stream>>>(hist, startArr, cursor);
  k_perm<<<N_SRC/256, 256, 0, stream>>>(labels, cursor, gidx, sortedLab);

  k_norm_split<<<N_TGT/4, 256, 0, stream>>>(T, nullptr, Thi, Tlo);
  k_norm_split<<<N_SRC/4, 256, 0, stream>>>(S, gidx, Shi, Slo);

  for (int j_off = 0; j_off < N_TGT; j_off += cols) {
    k_gemm<<<(N_SRC/128) * (cols/128), 256, 0, stream>>>(Thi, Tlo, Shi, Slo,
                                                         simbuf, cols, j_off);
    int thr = cols / 4; if (thr < 64) thr = 64;
    k_part1t4<<<NS, thr, 0, stream>>>(simbuf, cols, p1v, p1i, pse);
    k_assign<<<cols/4, 256, 0, stream>>>(p1v, p1i, sortedLab, assigned, cols, j_off);
    k_part2n<<<cols/4, 256, 0, stream>>>(simbuf, assigned, startArr, p1v, pse,
                                         scores, contrastA, cols, j_off);
  }
  k_finalize<<<1, 1024, 0, stream>>>(scores, contrastA, out);
}